// Round 4
// baseline (111.572 us; speedup 1.0000x reference)
//
#include <hip/hip_runtime.h>

// B=8, M=12, N=32, D=256, C=1024, O=512, BM=96.
//
// Algebra: ef = P @ S (S = row sums of x), so h = relu(W1@ef) = relu(A1@S),
// A1[o][n] = (R1[o][n] + 2*C1[o][n] - W1[o][33n]) / 512, precomputed from W1.
//
// ws layout (floats):
//   A1t  [32][512]   A1 transposed (n-major)   off 0      len 16384
//   Sg   [96][32]    row sums                  off 16384  len 3072
//   covg [96][1024]  cov = G - S S^T/256       off 19456  len 98304
//   Et   [96][1024]  sigmoid MLP output        off 117760 len 98304

__device__ __forceinline__ float sum4(float4 v){ return v.x+v.y+v.z+v.w; }
__device__ __forceinline__ float dot4(float4 a, float4 b){
    return a.x*b.x + a.y*b.y + a.z*b.z + a.w*b.w;
}
__device__ __forceinline__ void fma4s(float4& a, float s, float4 v){
    a.x += s*v.x; a.y += s*v.y; a.z += s*v.z; a.w += s*v.w;
}

// ---------------- k1: A1 precompute (bid<128) | S + Gram + cov (bid>=128) ---
__global__ __launch_bounds__(256) void k1(const float* __restrict__ x,
                                          const float* __restrict__ W1,
                                          float* __restrict__ A1t,
                                          float* __restrict__ Sg,
                                          float* __restrict__ covg) {
    int bid = blockIdx.x;
    if (bid < 128) {
        // wave w handles o = bid*4+w; lane l covers f4 idx {l, l+64, l+128, l+192}
        __shared__ float Rl[4][32];
        __shared__ float Cl[4][32];
        int w = threadIdx.x >> 6, l = threadIdx.x & 63;
        int o = bid*4 + w;
        const float4* W14 = (const float4*)(W1 + o*1024);
        float4 v0 = W14[l], v1 = W14[l+64], v2 = W14[l+128], v3 = W14[l+192];
        // R1[n]: n = (l>>3) + 8i — reduce over 8 consecutive lanes
        float r0 = sum4(v0), r1 = sum4(v1), r2 = sum4(v2), r3 = sum4(v3);
        #pragma unroll
        for (int m = 1; m < 8; m <<= 1) {
            r0 += __shfl_xor(r0, m, 8);
            r1 += __shfl_xor(r1, m, 8);
            r2 += __shfl_xor(r2, m, 8);
            r3 += __shfl_xor(r3, m, 8);
        }
        // C1[k]: k = 4*(l&7)+comp — sum i, then xor-reduce strides 8,16,32
        float4 cp;
        cp.x = v0.x+v1.x+v2.x+v3.x; cp.y = v0.y+v1.y+v2.y+v3.y;
        cp.z = v0.z+v1.z+v2.z+v3.z; cp.w = v0.w+v1.w+v2.w+v3.w;
        #pragma unroll
        for (int m = 8; m < 64; m <<= 1) {
            cp.x += __shfl_xor(cp.x, m);
            cp.y += __shfl_xor(cp.y, m);
            cp.z += __shfl_xor(cp.z, m);
            cp.w += __shfl_xor(cp.w, m);
        }
        if ((l & 7) == 0) {
            int nb = l >> 3;
            Rl[w][nb]    = r0; Rl[w][nb+8]  = r1;
            Rl[w][nb+16] = r2; Rl[w][nb+24] = r3;
        }
        if (l < 8) *((float4*)&Cl[w][l*4]) = cp;
        __syncthreads();
        if (l < 32) {
            float a = (Rl[w][l] + 2.f*Cl[w][l] - W1[o*1024 + 33*l]) * (1.f/512.f);
            A1t[l*512 + o] = a;
        }
    } else {
        int bm = bid - 128;
        int t = threadIdx.x;
        __shared__ float4 xs4[32][65];       // full 32x256 tile
        __shared__ float Gp[8][32][36];      // Gram partials, conflict-free pad
        __shared__ alignas(16) float S_l[32];
        const float4* x4 = (const float4*)x;
        #pragma unroll
        for (int i = 0; i < 8; ++i) {
            int idx = t + 256*i;
            xs4[idx >> 6][idx & 63] = x4[bm*2048 + idx];
        }
        __syncthreads();
        // row sums
        {
            int n = t >> 3, dq = t & 7;
            float s = 0.f;
            #pragma unroll
            for (int j = 0; j < 8; ++j) s += sum4(xs4[n][dq + 8*j]);
            s += __shfl_xor(s, 1, 8);
            s += __shfl_xor(s, 2, 8);
            s += __shfl_xor(s, 4, 8);
            if (dq == 0) { S_l[n] = s; Sg[bm*32 + n] = s; }
        }
        // Gram partials: 8 q-slices x (8 rt x 4 ct) threads, 4x8 tiles
        {
            int qs = t >> 5, tid = t & 31, rt = tid >> 2, ct = tid & 3;
            float g[4][8];
            #pragma unroll
            for (int i = 0; i < 4; ++i)
                #pragma unroll
                for (int j = 0; j < 8; ++j) g[i][j] = 0.f;
            #pragma unroll
            for (int qq = 0; qq < 8; ++qq) {
                int q = qs*8 + qq;
                float4 a0 = xs4[rt][q],    a1 = xs4[rt+8][q];
                float4 a2 = xs4[rt+16][q], a3 = xs4[rt+24][q];
                #pragma unroll
                for (int j = 0; j < 8; ++j) {
                    float4 b = xs4[ct + 4*j][q];
                    g[0][j] += dot4(a0, b); g[1][j] += dot4(a1, b);
                    g[2][j] += dot4(a2, b); g[3][j] += dot4(a3, b);
                }
            }
            #pragma unroll
            for (int i = 0; i < 4; ++i)
                #pragma unroll
                for (int j = 0; j < 8; ++j)
                    Gp[qs][rt + 8*i][ct + 4*j] = g[i][j];
        }
        __syncthreads();
        // reduce partials + cov = G - S S^T / 256
        {
            int n = t >> 3, k0 = (t & 7)*4;
            float4 g = {0.f,0.f,0.f,0.f};
            #pragma unroll
            for (int qs = 0; qs < 8; ++qs) {
                float4 p = *((const float4*)&Gp[qs][n][k0]);
                g.x += p.x; g.y += p.y; g.z += p.z; g.w += p.w;
            }
            float sn = S_l[n] * (1.f/256.f);
            float4 sk = *((const float4*)&S_l[k0]);
            float4 cv;
            cv.x = g.x - sn*sk.x; cv.y = g.y - sn*sk.y;
            cv.z = g.z - sn*sk.z; cv.w = g.w - sn*sk.w;
            ((float4*)covg)[bm*256 + t] = cv;
        }
    }
}

// ---------------- k2: h = relu(A1@S) fused with E = sigmoid(W2@h) -----------
// grid (16 cT x 12 bmG); block 256.
__global__ __launch_bounds__(256) void k2(const float* __restrict__ W2,
                                          const float* __restrict__ A1t,
                                          const float* __restrict__ Sg,
                                          float* __restrict__ Et) {
    __shared__ alignas(16) float S_l[8][32];
    __shared__ float hl[8][516];    // pad 4
    int t = threadIdx.x;
    int cT = blockIdx.x, bmG = blockIdx.y;
    {
        int bl = t >> 5, n = t & 31;
        S_l[bl][n] = Sg[(bmG*8 + bl)*32 + n];
    }
    __syncthreads();
    // h-phase: thread (blh = t>>5, ol = t&31) computes h[blh][o] for 128 f4
    {
        int blh = t >> 5, ol = t & 31;
        float4 sr[8];
        #pragma unroll
        for (int n4 = 0; n4 < 8; ++n4)
            sr[n4] = *((const float4*)&S_l[blh][n4*4]);
        float4 h0 = {0,0,0,0}, h1 = {0,0,0,0}, h2 = {0,0,0,0}, h3 = {0,0,0,0};
        const float4* A4 = (const float4*)A1t;
        #pragma unroll
        for (int n4 = 0; n4 < 8; ++n4) {
            float4 s4 = sr[n4];
            #pragma unroll
            for (int nc = 0; nc < 4; ++nc) {
                float s = (nc==0) ? s4.x : (nc==1) ? s4.y : (nc==2) ? s4.z : s4.w;
                int n = n4*4 + nc;
                fma4s(h0, s, A4[n*128 + ol]);
                fma4s(h1, s, A4[n*128 + 32 + ol]);
                fma4s(h2, s, A4[n*128 + 64 + ol]);
                fma4s(h3, s, A4[n*128 + 96 + ol]);
            }
        }
        h0.x=fmaxf(h0.x,0.f); h0.y=fmaxf(h0.y,0.f); h0.z=fmaxf(h0.z,0.f); h0.w=fmaxf(h0.w,0.f);
        h1.x=fmaxf(h1.x,0.f); h1.y=fmaxf(h1.y,0.f); h1.z=fmaxf(h1.z,0.f); h1.w=fmaxf(h1.w,0.f);
        h2.x=fmaxf(h2.x,0.f); h2.y=fmaxf(h2.y,0.f); h2.z=fmaxf(h2.z,0.f); h2.w=fmaxf(h2.w,0.f);
        h3.x=fmaxf(h3.x,0.f); h3.y=fmaxf(h3.y,0.f); h3.z=fmaxf(h3.z,0.f); h3.w=fmaxf(h3.w,0.f);
        *((float4*)&hl[blh][ol*4])        = h0;
        *((float4*)&hl[blh][(ol+32)*4])   = h1;
        *((float4*)&hl[blh][(ol+64)*4])   = h2;
        *((float4*)&hl[blh][(ol+96)*4])   = h3;
    }
    __syncthreads();
    // main GEMM2: thread (olane = t&15, cg = t>>4) handles c0..c0+3
    {
        int olane = t & 15, cg = t >> 4;
        int c0 = cT*64 + cg*4;
        float acc[4][8];
        #pragma unroll
        for (int ci = 0; ci < 4; ++ci)
            #pragma unroll
            for (int bl = 0; bl < 8; ++bl) acc[ci][bl] = 0.f;
        const float4* W24 = (const float4*)W2;
        #pragma unroll
        for (int oo = 0; oo < 8; ++oo) {
            float4 w0 = W24[(c0+0)*128 + oo*16 + olane];
            float4 w1 = W24[(c0+1)*128 + oo*16 + olane];
            float4 w2 = W24[(c0+2)*128 + oo*16 + olane];
            float4 w3 = W24[(c0+3)*128 + oo*16 + olane];
            #pragma unroll
            for (int bl = 0; bl < 8; ++bl) {
                float4 h4 = *((const float4*)&hl[bl][(oo*16 + olane)*4]);
                acc[0][bl] += dot4(w0, h4);
                acc[1][bl] += dot4(w1, h4);
                acc[2][bl] += dot4(w2, h4);
                acc[3][bl] += dot4(w3, h4);
            }
        }
        #pragma unroll
        for (int ci = 0; ci < 4; ++ci)
            #pragma unroll
            for (int bl = 0; bl < 8; ++bl) {
                float a = acc[ci][bl];
                a += __shfl_xor(a, 1, 16);
                a += __shfl_xor(a, 2, 16);
                a += __shfl_xor(a, 4, 16);
                a += __shfl_xor(a, 8, 16);
                acc[ci][bl] = a;
            }
        if (olane == 0) {
            #pragma unroll
            for (int ci = 0; ci < 4; ++ci)
                #pragma unroll
                for (int bl = 0; bl < 8; ++bl)
                    Et[(bmG*8 + bl)*1024 + c0 + ci] =
                        1.f / (1.f + __expf(-acc[ci][bl]));
        }
    }
}

// ---------------- k4: mask + softmax + att@x (per bm x d-half) --------------
// grid 192 = 96 bm x 2 halves; block 256; ONE __syncthreads.
__global__ __launch_bounds__(256) void k4(const float* __restrict__ x,
                                          const float* __restrict__ covg,
                                          const float* __restrict__ Et,
                                          float* __restrict__ out) {
    int bm = blockIdx.x >> 1;
    int h  = blockIdx.x & 1;
    int t  = threadIdx.x;
    __shared__ float4 xs4[32][33];      // this d-half of x
    __shared__ float att_l[32][36];
    const float4* x4 = (const float4*)x;
    #pragma unroll
    for (int i = 0; i < 4; ++i) {
        int idx = t + 256*i;
        int n = idx >> 5, dq = idx & 31;
        xs4[n][dq] = x4[bm*2048 + n*64 + h*32 + dq];
    }
    // logits + softmax: thread t owns f4 entry t (row t>>3, cols 4*(t&7));
    // softmax reads only its own entry + width-8 shfl -> no barrier needed.
    {
        float4 cv = ((const float4*)covg)[bm*256 + t];
        float4 e  = ((const float4*)Et)[bm*256 + t];
        float4 lg;
        lg.x = cv.x > 0.f ? e.x : -1e12f;
        lg.y = cv.y > 0.f ? e.y : -1e12f;
        lg.z = cv.z > 0.f ? e.z : -1e12f;
        lg.w = cv.w > 0.f ? e.w : -1e12f;
        float m = fmaxf(fmaxf(lg.x, lg.y), fmaxf(lg.z, lg.w));
        m = fmaxf(m, __shfl_xor(m, 1, 8));
        m = fmaxf(m, __shfl_xor(m, 2, 8));
        m = fmaxf(m, __shfl_xor(m, 4, 8));
        float4 p;
        p.x = __expf(lg.x - m); p.y = __expf(lg.y - m);
        p.z = __expf(lg.z - m); p.w = __expf(lg.w - m);
        float s = p.x + p.y + p.z + p.w;
        s += __shfl_xor(s, 1, 8);
        s += __shfl_xor(s, 2, 8);
        s += __shfl_xor(s, 4, 8);
        float inv = 1.f / s;
        p.x *= inv; p.y *= inv; p.z *= inv; p.w *= inv;
        *((float4*)&att_l[t >> 3][(t & 7)*4]) = p;
    }
    __syncthreads();
    // PV: thread (txl = t&31 f4-col, wy = t>>5 row-group of 4)
    {
        int txl = t & 31, wy = t >> 5;
        int r0 = wy*4;
        float4 acc0={0,0,0,0}, acc1={0,0,0,0}, acc2={0,0,0,0}, acc3={0,0,0,0};
        #pragma unroll
        for (int kq = 0; kq < 8; ++kq) {
            float4 xa = xs4[kq*4+0][txl];
            float4 xb = xs4[kq*4+1][txl];
            float4 xc = xs4[kq*4+2][txl];
            float4 xd = xs4[kq*4+3][txl];
            float4 w0 = *((const float4*)&att_l[r0+0][kq*4]);
            float4 w1 = *((const float4*)&att_l[r0+1][kq*4]);
            float4 w2 = *((const float4*)&att_l[r0+2][kq*4]);
            float4 w3 = *((const float4*)&att_l[r0+3][kq*4]);
            fma4s(acc0,w0.x,xa); fma4s(acc0,w0.y,xb); fma4s(acc0,w0.z,xc); fma4s(acc0,w0.w,xd);
            fma4s(acc1,w1.x,xa); fma4s(acc1,w1.y,xb); fma4s(acc1,w1.z,xc); fma4s(acc1,w1.w,xd);
            fma4s(acc2,w2.x,xa); fma4s(acc2,w2.y,xb); fma4s(acc2,w2.z,xc); fma4s(acc2,w2.w,xd);
            fma4s(acc3,w3.x,xa); fma4s(acc3,w3.y,xb); fma4s(acc3,w3.z,xc); fma4s(acc3,w3.w,xd);
        }
        float4* out4 = (float4*)out;
        out4[bm*2048 + (r0+0)*64 + h*32 + txl] = acc0;
        out4[bm*2048 + (r0+1)*64 + h*32 + txl] = acc1;
        out4[bm*2048 + (r0+2)*64 + h*32 + txl] = acc2;
        out4[bm*2048 + (r0+3)*64 + h*32 + txl] = acc3;
    }
}

extern "C" void kernel_launch(void* const* d_in, const int* in_sizes, int n_in,
                              void* d_out, int out_size, void* d_ws, size_t ws_size,
                              hipStream_t stream) {
    const float* x  = (const float*)d_in[0];
    const float* W1 = (const float*)d_in[1];
    const float* W2 = (const float*)d_in[2];
    float* out = (float*)d_out;
    float* ws  = (float*)d_ws;

    float* A1t  = ws;               // 16384 floats
    float* Sg   = ws + 16384;       // 3072
    float* covg = ws + 19456;       // 98304
    float* Et   = ws + 117760;      // 98304

    k1<<<224, 256, 0, stream>>>(x, W1, A1t, Sg, covg);
    k2<<<dim3(16, 12), 256, 0, stream>>>(W2, A1t, Sg, Et);
    k4<<<192, 256, 0, stream>>>(x, covg, Et, out);
}

// Round 5
// 86.907 us; speedup vs baseline: 1.2838x; 1.2838x over previous
//
#include <hip/hip_runtime.h>

// B=8, M=12, N=32, D=256, C=1024, O=512, BM=96.
//
// Algebra: ef = P @ S (S = row sums of x), so h = relu(W1@ef) = relu(A1@S),
// A1[o][n] = (R1[o][n] + 2*C1[o][n] - W1[o][33n]) / 512, precomputed from W1.
//
// ws layout (floats):
//   A1t  [32][512]   A1 transposed (n-major)   off 0      len 16384
//   Sg   [96][32]    row sums                  off 16384  len 3072
//   covg [96][1024]  cov = G - S S^T/256       off 19456  len 98304
//   Et   [96][1024]  sigmoid MLP output        off 117760 len 98304

__device__ __forceinline__ float sum4(float4 v){ return v.x+v.y+v.z+v.w; }
__device__ __forceinline__ float dot4(float4 a, float4 b){
    return a.x*b.x + a.y*b.y + a.z*b.z + a.w*b.w;
}
__device__ __forceinline__ void fma4s(float4& a, float s, float4 v){
    a.x += s*v.x; a.y += s*v.y; a.z += s*v.z; a.w += s*v.w;
}

// ---------------- k1: A1 precompute (bid<128) | S + Gram + cov (bid>=128) ---
__global__ __launch_bounds__(256) void k1(const float* __restrict__ x,
                                          const float* __restrict__ W1,
                                          float* __restrict__ A1t,
                                          float* __restrict__ Sg,
                                          float* __restrict__ covg) {
    int bid = blockIdx.x;
    if (bid < 128) {
        __shared__ float Rl[4][32];
        __shared__ float Cl[4][32];
        int w = threadIdx.x >> 6, l = threadIdx.x & 63;
        int o = bid*4 + w;
        const float4* W14 = (const float4*)(W1 + o*1024);
        float4 v0 = W14[l], v1 = W14[l+64], v2 = W14[l+128], v3 = W14[l+192];
        float r0 = sum4(v0), r1 = sum4(v1), r2 = sum4(v2), r3 = sum4(v3);
        #pragma unroll
        for (int m = 1; m < 8; m <<= 1) {
            r0 += __shfl_xor(r0, m, 8);
            r1 += __shfl_xor(r1, m, 8);
            r2 += __shfl_xor(r2, m, 8);
            r3 += __shfl_xor(r3, m, 8);
        }
        float4 cp;
        cp.x = v0.x+v1.x+v2.x+v3.x; cp.y = v0.y+v1.y+v2.y+v3.y;
        cp.z = v0.z+v1.z+v2.z+v3.z; cp.w = v0.w+v1.w+v2.w+v3.w;
        #pragma unroll
        for (int m = 8; m < 64; m <<= 1) {
            cp.x += __shfl_xor(cp.x, m);
            cp.y += __shfl_xor(cp.y, m);
            cp.z += __shfl_xor(cp.z, m);
            cp.w += __shfl_xor(cp.w, m);
        }
        if ((l & 7) == 0) {
            int nb = l >> 3;
            Rl[w][nb]    = r0; Rl[w][nb+8]  = r1;
            Rl[w][nb+16] = r2; Rl[w][nb+24] = r3;
        }
        if (l < 8) *((float4*)&Cl[w][l*4]) = cp;
        __syncthreads();
        if (l < 32) {
            float a = (Rl[w][l] + 2.f*Cl[w][l] - W1[o*1024 + 33*l]) * (1.f/512.f);
            A1t[l*512 + o] = a;
        }
    } else {
        int bm = bid - 128;
        int t = threadIdx.x;
        __shared__ float4 xs4[32][65];
        __shared__ float Gp[8][32][36];
        __shared__ alignas(16) float S_l[32];
        const float4* x4 = (const float4*)x;
        #pragma unroll
        for (int i = 0; i < 8; ++i) {
            int idx = t + 256*i;
            xs4[idx >> 6][idx & 63] = x4[bm*2048 + idx];
        }
        __syncthreads();
        {
            int n = t >> 3, dq = t & 7;
            float s = 0.f;
            #pragma unroll
            for (int j = 0; j < 8; ++j) s += sum4(xs4[n][dq + 8*j]);
            s += __shfl_xor(s, 1, 8);
            s += __shfl_xor(s, 2, 8);
            s += __shfl_xor(s, 4, 8);
            if (dq == 0) { S_l[n] = s; Sg[bm*32 + n] = s; }
        }
        {
            int qs = t >> 5, tid = t & 31, rt = tid >> 2, ct = tid & 3;
            float g[4][8];
            #pragma unroll
            for (int i = 0; i < 4; ++i)
                #pragma unroll
                for (int j = 0; j < 8; ++j) g[i][j] = 0.f;
            #pragma unroll
            for (int qq = 0; qq < 8; ++qq) {
                int q = qs*8 + qq;
                float4 a0 = xs4[rt][q],    a1 = xs4[rt+8][q];
                float4 a2 = xs4[rt+16][q], a3 = xs4[rt+24][q];
                #pragma unroll
                for (int j = 0; j < 8; ++j) {
                    float4 b = xs4[ct + 4*j][q];
                    g[0][j] += dot4(a0, b); g[1][j] += dot4(a1, b);
                    g[2][j] += dot4(a2, b); g[3][j] += dot4(a3, b);
                }
            }
            #pragma unroll
            for (int i = 0; i < 4; ++i)
                #pragma unroll
                for (int j = 0; j < 8; ++j)
                    Gp[qs][rt + 8*i][ct + 4*j] = g[i][j];
        }
        __syncthreads();
        {
            int n = t >> 3, k0 = (t & 7)*4;
            float4 g = {0.f,0.f,0.f,0.f};
            #pragma unroll
            for (int qs = 0; qs < 8; ++qs) {
                float4 p = *((const float4*)&Gp[qs][n][k0]);
                g.x += p.x; g.y += p.y; g.z += p.z; g.w += p.w;
            }
            float sn = S_l[n] * (1.f/256.f);
            float4 sk = *((const float4*)&S_l[k0]);
            float4 cv;
            cv.x = g.x - sn*sk.x; cv.y = g.y - sn*sk.y;
            cv.z = g.z - sn*sk.z; cv.w = g.w - sn*sk.w;
            ((float4*)covg)[bm*256 + t] = cv;
        }
    }
}

// ---------------- k2: h = relu(A1@S) fused with E = sigmoid(W2@h) -----------
// grid (16 cT x 12 bmG); block 256. Minimal register arrays (no spill):
// h-phase one float4 accumulator at a time; GEMM2 with scalar acc[8],
// ci-sequential over 4 c's per 16-lane group.
__global__ __launch_bounds__(256) void k2(const float* __restrict__ W2,
                                          const float* __restrict__ A1t,
                                          const float* __restrict__ Sg,
                                          float* __restrict__ Et) {
    __shared__ alignas(16) float S_l[8][32];
    __shared__ float hl[8][516];    // pad 4
    int t = threadIdx.x;
    int cT = blockIdx.x, bmG = blockIdx.y;
    {
        int bl = t >> 5, n = t & 31;
        S_l[bl][n] = Sg[(bmG*8 + bl)*32 + n];
    }
    __syncthreads();
    // h-phase: 1024 f4 outputs (8 bm x 128), 4 per thread, sequential.
    {
        const float4* A4 = (const float4*)A1t;
        #pragma unroll
        for (int part = 0; part < 4; ++part) {
            int o4 = part*256 + t;          // 0..1023
            int bl = o4 >> 7, ol = o4 & 127;
            float4 hacc = {0.f,0.f,0.f,0.f};
            #pragma unroll 8
            for (int n = 0; n < 32; ++n)
                fma4s(hacc, S_l[bl][n], A4[n*128 + ol]);
            hacc.x = fmaxf(hacc.x, 0.f); hacc.y = fmaxf(hacc.y, 0.f);
            hacc.z = fmaxf(hacc.z, 0.f); hacc.w = fmaxf(hacc.w, 0.f);
            *((float4*)&hl[bl][ol*4]) = hacc;
        }
    }
    __syncthreads();
    // GEMM2: (olane = t&15, cg = t>>4); each group does c = cT*64+cg*4+ci.
    {
        int olane = t & 15, cg = t >> 4;
        const float4* W24 = (const float4*)W2;
        #pragma unroll
        for (int ci = 0; ci < 4; ++ci) {
            int c = cT*64 + cg*4 + ci;
            float acc[8] = {0.f,0.f,0.f,0.f,0.f,0.f,0.f,0.f};
            #pragma unroll
            for (int oo = 0; oo < 8; ++oo) {
                float4 w = W24[c*128 + oo*16 + olane];
                #pragma unroll
                for (int bl = 0; bl < 8; ++bl)
                    acc[bl] += dot4(w, *((const float4*)&hl[bl][(oo*16+olane)*4]));
            }
            #pragma unroll
            for (int bl = 0; bl < 8; ++bl) {
                float a = acc[bl];
                a += __shfl_xor(a, 1, 16);
                a += __shfl_xor(a, 2, 16);
                a += __shfl_xor(a, 4, 16);
                a += __shfl_xor(a, 8, 16);
                if (olane == 0)
                    Et[(bmG*8 + bl)*1024 + c] = 1.f / (1.f + __expf(-a));
            }
        }
    }
}

// ---------------- k4: mask + softmax + att@x (per bm x d-half) --------------
// grid 192 = 96 bm x 2 halves; block 256; ONE __syncthreads.
__global__ __launch_bounds__(256) void k4(const float* __restrict__ x,
                                          const float* __restrict__ covg,
                                          const float* __restrict__ Et,
                                          float* __restrict__ out) {
    int bm = blockIdx.x >> 1;
    int h  = blockIdx.x & 1;
    int t  = threadIdx.x;
    __shared__ float4 xs4[32][33];
    __shared__ float att_l[32][36];
    const float4* x4 = (const float4*)x;
    #pragma unroll
    for (int i = 0; i < 4; ++i) {
        int idx = t + 256*i;
        int n = idx >> 5, dq = idx & 31;
        xs4[n][dq] = x4[bm*2048 + n*64 + h*32 + dq];
    }
    {
        float4 cv = ((const float4*)covg)[bm*256 + t];
        float4 e  = ((const float4*)Et)[bm*256 + t];
        float4 lg;
        lg.x = cv.x > 0.f ? e.x : -1e12f;
        lg.y = cv.y > 0.f ? e.y : -1e12f;
        lg.z = cv.z > 0.f ? e.z : -1e12f;
        lg.w = cv.w > 0.f ? e.w : -1e12f;
        float m = fmaxf(fmaxf(lg.x, lg.y), fmaxf(lg.z, lg.w));
        m = fmaxf(m, __shfl_xor(m, 1, 8));
        m = fmaxf(m, __shfl_xor(m, 2, 8));
        m = fmaxf(m, __shfl_xor(m, 4, 8));
        float4 p;
        p.x = __expf(lg.x - m); p.y = __expf(lg.y - m);
        p.z = __expf(lg.z - m); p.w = __expf(lg.w - m);
        float s = p.x + p.y + p.z + p.w;
        s += __shfl_xor(s, 1, 8);
        s += __shfl_xor(s, 2, 8);
        s += __shfl_xor(s, 4, 8);
        float inv = 1.f / s;
        p.x *= inv; p.y *= inv; p.z *= inv; p.w *= inv;
        *((float4*)&att_l[t >> 3][(t & 7)*4]) = p;
    }
    __syncthreads();
    {
        int txl = t & 31, wy = t >> 5;
        int r0 = wy*4;
        float4 acc0={0,0,0,0}, acc1={0,0,0,0}, acc2={0,0,0,0}, acc3={0,0,0,0};
        #pragma unroll
        for (int kq = 0; kq < 8; ++kq) {
            float4 xa = xs4[kq*4+0][txl];
            float4 xb = xs4[kq*4+1][txl];
            float4 xc = xs4[kq*4+2][txl];
            float4 xd = xs4[kq*4+3][txl];
            float4 w0 = *((const float4*)&att_l[r0+0][kq*4]);
            float4 w1 = *((const float4*)&att_l[r0+1][kq*4]);
            float4 w2 = *((const float4*)&att_l[r0+2][kq*4]);
            float4 w3 = *((const float4*)&att_l[r0+3][kq*4]);
            fma4s(acc0,w0.x,xa); fma4s(acc0,w0.y,xb); fma4s(acc0,w0.z,xc); fma4s(acc0,w0.w,xd);
            fma4s(acc1,w1.x,xa); fma4s(acc1,w1.y,xb); fma4s(acc1,w1.z,xc); fma4s(acc1,w1.w,xd);
            fma4s(acc2,w2.x,xa); fma4s(acc2,w2.y,xb); fma4s(acc2,w2.z,xc); fma4s(acc2,w2.w,xd);
            fma4s(acc3,w3.x,xa); fma4s(acc3,w3.y,xb); fma4s(acc3,w3.z,xc); fma4s(acc3,w3.w,xd);
        }
        float4* out4 = (float4*)out;
        out4[bm*2048 + (r0+0)*64 + h*32 + txl] = acc0;
        out4[bm*2048 + (r0+1)*64 + h*32 + txl] = acc1;
        out4[bm*2048 + (r0+2)*64 + h*32 + txl] = acc2;
        out4[bm*2048 + (r0+3)*64 + h*32 + txl] = acc3;
    }
}

extern "C" void kernel_launch(void* const* d_in, const int* in_sizes, int n_in,
                              void* d_out, int out_size, void* d_ws, size_t ws_size,
                              hipStream_t stream) {
    const float* x  = (const float*)d_in[0];
    const float* W1 = (const float*)d_in[1];
    const float* W2 = (const float*)d_in[2];
    float* out = (float*)d_out;
    float* ws  = (float*)d_ws;

    float* A1t  = ws;               // 16384 floats
    float* Sg   = ws + 16384;       // 3072
    float* covg = ws + 19456;       // 98304
    float* Et   = ws + 117760;      // 98304

    k1<<<224, 256, 0, stream>>>(x, W1, A1t, Sg, covg);
    k2<<<dim3(16, 12), 256, 0, stream>>>(W2, A1t, Sg, Et);
    k4<<<192, 256, 0, stream>>>(x, covg, Et, out);
}